// Round 2
// baseline (586.999 us; speedup 1.0000x reference)
//
#include <hip/hip_runtime.h>

#define SEQ   1024
#define BATCH 512
#define NTAGS 48

// One wave (64 lanes) per batch chain. Lane j owns W[:,j] (exp of transitions
// column) in registers and the running linear-domain score a[j]; shared log
// offset c. Per step: a'[j] = (sum_i a[i]*W[i,j]) * exp(em[t,j]), renormalized
// by the lane-max every 4 steps to avoid fp32 overflow.
__global__ __launch_bounds__(64) void crf_chain_kernel(
    const float* __restrict__ em,     // [SEQ,BATCH,NTAGS] f32
    const int*   __restrict__ tags,   // [SEQ,BATCH] int32 (harness converts int64 -> int32)
    const int*   __restrict__ mask,   // [SEQ,BATCH] int32
    const float* __restrict__ start_t,// [NTAGS]
    const float* __restrict__ end_t,  // [NTAGS]
    const float* __restrict__ trans,  // [NTAGS,NTAGS]
    float*       __restrict__ llh)    // [BATCH] out: per-chain log-likelihood
{
  const int b    = blockIdx.x;
  const int lane = threadIdx.x;          // 0..63
  const bool act = lane < NTAGS;
  const int jj   = act ? lane : 0;       // clamp for safe loads

  __shared__ float sa[64];               // broadcast buffer for a[]

  // W column: wcol[i] = exp(trans[i][jj])  (coalesced loads: lanes contiguous)
  float wcol[NTAGS];
#pragma unroll
  for (int i = 0; i < NTAGS; ++i)
    wcol[i] = __expf(trans[i * NTAGS + jj]);

  // init: score0[j] = start[j] + em[0,b,j];  a = exp(score0), c = 0
  float c = 0.0f;
  float s0 = start_t[jj] + em[(size_t)b * NTAGS + jj];
  float a  = act ? __expf(s0) : 0.0f;

  const size_t strideT = (size_t)BATCH * NTAGS;

  // software-pipelined emission / mask loads
  float em_cur = em[strideT + (size_t)b * NTAGS + jj];
  int   mk_cur = mask[BATCH + b];

  for (int t = 1; t < SEQ; ++t) {
    float em_nxt = 0.0f;
    int   mk_nxt = 0;
    if (t + 1 < SEQ) {
      em_nxt = em[(size_t)(t + 1) * strideT + (size_t)b * NTAGS + jj];
      mk_nxt = mask[(t + 1) * BATCH + b];
    }

    sa[lane] = a;                        // lanes >=48 write 0
    __syncthreads();

    float acc0 = 0.f, acc1 = 0.f, acc2 = 0.f, acc3 = 0.f;
#pragma unroll
    for (int i = 0; i < NTAGS; i += 4) {
      float4 v = *(const float4*)&sa[i];   // ds_read_b128 broadcast
      acc0 = fmaf(v.x, wcol[i + 0], acc0);
      acc1 = fmaf(v.y, wcol[i + 1], acc1);
      acc2 = fmaf(v.z, wcol[i + 2], acc2);
      acc3 = fmaf(v.w, wcol[i + 3], acc3);
    }
    __syncthreads();

    float s   = (acc0 + acc1) + (acc2 + acc3);
    float nxt = s * __expf(em_cur);
    if (mk_cur != 0) a = act ? nxt : 0.0f;   // mask==0 -> keep old score

    if ((t & 3) == 0) {                  // renormalize: keep max(a) ~ 1
      float m = a;
#pragma unroll
      for (int off = 32; off > 0; off >>= 1)
        m = fmaxf(m, __shfl_xor(m, off));
      c += __logf(m);
      a *= __builtin_amdgcn_rcpf(m);
    }

    em_cur = em_nxt;
    mk_cur = mk_nxt;
  }

  // denominator: c + log(sum_j a[j]*exp(end[j]))
  float v = act ? a * __expf(end_t[jj]) : 0.0f;
#pragma unroll
  for (int off = 32; off > 0; off >>= 1)
    v += __shfl_xor(v, off);
  float den = c + __logf(v);

  // numerator: tag-path score; lanes parallel over t
  float np = 0.0f;
  int   mcount = 0;
  for (int t = lane; t < SEQ; t += 64) {
    int   tag_t = tags[(size_t)t * BATCH + b];
    tag_t = min(max(tag_t, 0), NTAGS - 1);      // safety clamp
    int   mk    = mask[t * BATCH + b];
    float e     = em[(size_t)t * strideT + (size_t)b * NTAGS + tag_t];
    if (t == 0) {
      np += start_t[tag_t] + e;
    } else {
      int tag_p = tags[(size_t)(t - 1) * BATCH + b];
      tag_p = min(max(tag_p, 0), NTAGS - 1);
      np += (trans[tag_p * NTAGS + tag_t] + e) * (float)mk;
    }
    mcount += (mk != 0) ? 1 : 0;
  }
#pragma unroll
  for (int off = 32; off > 0; off >>= 1) {
    np     += __shfl_xor(np, off);
    mcount += __shfl_xor(mcount, off);
  }
  int   last_idx = mcount - 1;                     // seq_ends
  last_idx = min(max(last_idx, 0), SEQ - 1);
  int   tag_last = tags[(size_t)last_idx * BATCH + b];
  tag_last = min(max(tag_last, 0), NTAGS - 1);
  float num      = np + end_t[tag_last];

  if (lane == 0) llh[b] = num - den;
}

__global__ __launch_bounds__(64) void crf_reduce_kernel(
    const float* __restrict__ llh, float* __restrict__ out)
{
  const int lane = threadIdx.x;
  float v = 0.0f;
#pragma unroll
  for (int k = 0; k < BATCH / 64; ++k)
    v += llh[lane + 64 * k];
#pragma unroll
  for (int off = 32; off > 0; off >>= 1)
    v += __shfl_xor(v, off);
  if (lane == 0) out[0] = v * (1.0f / (float)BATCH);
}

extern "C" void kernel_launch(void* const* d_in, const int* in_sizes, int n_in,
                              void* d_out, int out_size, void* d_ws, size_t ws_size,
                              hipStream_t stream) {
  const float* em   = (const float*)d_in[0];
  const int*   tg   = (const int*)  d_in[1];
  const int*   mask = (const int*)  d_in[2];
  const float* st   = (const float*)d_in[3];
  const float* en   = (const float*)d_in[4];
  const float* tr   = (const float*)d_in[5];
  float* llh = (float*)d_ws;           // BATCH floats of scratch

  crf_chain_kernel<<<BATCH, 64, 0, stream>>>(em, tg, mask, st, en, tr, llh);
  crf_reduce_kernel<<<1, 64, 0, stream>>>(llh, (float*)d_out);
}

// Round 3
// 388.998 us; speedup vs baseline: 1.5090x; 1.5090x over previous
//
#include <hip/hip_runtime.h>

#define SEQ   1024
#define BATCH 512
#define NTAGS 48

// One wave (64 lanes) per batch chain. Lane j owns W[:,j] = exp(trans[:,j]) in
// registers and the linear-domain score a[j]; shared log offset c.
// Per step: a'[j] = (sum_i a[i]*W[i,j]) * exp(em[t,j]); every 8th step the
// wave-uniform max of the incoming a (computed for free during the matvec)
// is divided out and absorbed into c.
// Single wave per block -> NO __syncthreads (avoids the vmcnt(0) barrier
// drain that put the HBM prefetch on the critical path); same-wave LDS RAW
// ordering via explicit s_waitcnt lgkmcnt(0).
__global__ __launch_bounds__(64) void crf_chain_kernel(
    const float* __restrict__ em,     // [SEQ,BATCH,NTAGS] f32
    const int*   __restrict__ tags,   // [SEQ,BATCH] int32
    const int*   __restrict__ mask,   // [SEQ,BATCH] int32
    const float* __restrict__ start_t,// [NTAGS]
    const float* __restrict__ end_t,  // [NTAGS]
    const float* __restrict__ trans,  // [NTAGS,NTAGS]
    float*       __restrict__ llh)    // [BATCH]
{
  const int b    = blockIdx.x;
  const int lane = threadIdx.x;          // 0..63, single wave
  const bool act = lane < NTAGS;
  const int jj   = act ? lane : 0;

  __shared__ __align__(16) float sa[64];
  __shared__ int smask[SEQ];

  // Stage this chain's mask column into LDS once; detect all-ones.
  int myall = 1;
#pragma unroll
  for (int k = 0; k < SEQ / 64; ++k) {
    int t = lane + 64 * k;
    int v = mask[(size_t)t * BATCH + b];
    smask[t] = v;
    myall &= (v != 0) ? 1 : 0;
  }
  const bool allones = (__ballot(myall != 0) == ~0ull);

  // W column in registers (coalesced: lanes read contiguous floats per row)
  float wcol[NTAGS];
#pragma unroll
  for (int i = 0; i < NTAGS; ++i)
    wcol[i] = __expf(trans[i * NTAGS + jj]);

  float c = 0.0f;
  float a = act ? __expf(start_t[jj] + em[(size_t)b * NTAGS + jj]) : 0.0f;

  const size_t strideT = (size_t)BATCH * NTAGS;
  const float* emb = em + (size_t)b * NTAGS + jj;

  // 4-deep emission prefetch: loads for t+1..t+4 in flight; exp() done one
  // iteration before use so it's off the per-step critical path.
  float ex_cur = __expf(emb[1 * strideT]);   // for t=1
  float em1 = emb[2 * strideT];
  float em2 = emb[3 * strideT];
  float em3 = emb[4 * strideT];

  asm volatile("s_waitcnt lgkmcnt(0)" ::: "memory");  // smask staged (1 wave)

  if (allones) {
    // ---------------- fast path: no mask logic ----------------
    for (int t = 1; t < SEQ; ++t) {
      int tp = (t + 4 < SEQ) ? (t + 4) : (SEQ - 1);
      float em_in = emb[(size_t)tp * strideT];     // prefetch

      sa[lane] = a;
      asm volatile("s_waitcnt lgkmcnt(0)" ::: "memory");

      if ((t & 7) == 1) {
        // renorm step: compute wave-uniform max of incoming a for free
        float acc0 = 0.f, acc1 = 0.f, acc2 = 0.f, acc3 = 0.f, mx = 0.f;
#pragma unroll
        for (int i = 0; i < NTAGS; i += 4) {
          float4 v = *(const float4*)&sa[i];
          acc0 = fmaf(v.x, wcol[i + 0], acc0);
          acc1 = fmaf(v.y, wcol[i + 1], acc1);
          acc2 = fmaf(v.z, wcol[i + 2], acc2);
          acc3 = fmaf(v.w, wcol[i + 3], acc3);
          mx = fmaxf(mx, fmaxf(fmaxf(v.x, v.y), fmaxf(v.z, v.w)));
        }
        float s  = (acc0 + acc1) + (acc2 + acc3);
        float rm = __builtin_amdgcn_rcpf(mx);
        c += __logf(mx);
        a = act ? (s * ex_cur) * rm : 0.0f;
      } else {
        float acc0 = 0.f, acc1 = 0.f, acc2 = 0.f, acc3 = 0.f;
#pragma unroll
        for (int i = 0; i < NTAGS; i += 4) {
          float4 v = *(const float4*)&sa[i];
          acc0 = fmaf(v.x, wcol[i + 0], acc0);
          acc1 = fmaf(v.y, wcol[i + 1], acc1);
          acc2 = fmaf(v.z, wcol[i + 2], acc2);
          acc3 = fmaf(v.w, wcol[i + 3], acc3);
        }
        float s = (acc0 + acc1) + (acc2 + acc3);
        a = act ? s * ex_cur : 0.0f;
      }

      ex_cur = __expf(em1); em1 = em2; em2 = em3; em3 = em_in;
    }
  } else {
    // ---------------- general path: mask from LDS ----------------
    int mk_cur = smask[1];
    int mk1    = smask[(2 < SEQ) ? 2 : SEQ - 1];
    for (int t = 1; t < SEQ; ++t) {
      int tp = (t + 4 < SEQ) ? (t + 4) : (SEQ - 1);
      float em_in = emb[(size_t)tp * strideT];

      sa[lane] = a;
      asm volatile("s_waitcnt lgkmcnt(0)" ::: "memory");

      float acc0 = 0.f, acc1 = 0.f, acc2 = 0.f, acc3 = 0.f, mx = 0.f;
#pragma unroll
      for (int i = 0; i < NTAGS; i += 4) {
        float4 v = *(const float4*)&sa[i];
        acc0 = fmaf(v.x, wcol[i + 0], acc0);
        acc1 = fmaf(v.y, wcol[i + 1], acc1);
        acc2 = fmaf(v.z, wcol[i + 2], acc2);
        acc3 = fmaf(v.w, wcol[i + 3], acc3);
        mx = fmaxf(mx, fmaxf(fmaxf(v.x, v.y), fmaxf(v.z, v.w)));
      }
      float s  = (acc0 + acc1) + (acc2 + acc3);
      float rm = 1.0f;
      if ((t & 7) == 1) { rm = __builtin_amdgcn_rcpf(mx); c += __logf(mx); }

      float na = act ? s * ex_cur : 0.0f;
      a = (mk_cur != 0 ? na : a) * rm;     // masked: keep old score (rescaled)

      int mk_in = smask[(t + 2 < SEQ) ? (t + 2) : (SEQ - 1)];
      mk_cur = mk1; mk1 = mk_in;
      ex_cur = __expf(em1); em1 = em2; em2 = em3; em3 = em_in;
    }
  }

  // denominator: c + log(sum_j a[j]*exp(end[j]))
  float v = act ? a * __expf(end_t[jj]) : 0.0f;
#pragma unroll
  for (int off = 32; off > 0; off >>= 1)
    v += __shfl_xor(v, off);
  float den = c + __logf(v);

  // numerator: tag-path score; lanes parallel over t
  float np = 0.0f;
  int   mcount = 0;
  for (int t = lane; t < SEQ; t += 64) {
    int tag_t = tags[(size_t)t * BATCH + b];
    tag_t = min(max(tag_t, 0), NTAGS - 1);
    int mk = smask[t];
    float e = em[(size_t)t * strideT + (size_t)b * NTAGS + tag_t];
    if (t == 0) {
      np += start_t[tag_t] + e;
    } else {
      int tag_p = tags[(size_t)(t - 1) * BATCH + b];
      tag_p = min(max(tag_p, 0), NTAGS - 1);
      np += (trans[tag_p * NTAGS + tag_t] + e) * (float)mk;
    }
    mcount += (mk != 0) ? 1 : 0;
  }
#pragma unroll
  for (int off = 32; off > 0; off >>= 1) {
    np     += __shfl_xor(np, off);
    mcount += __shfl_xor(mcount, off);
  }
  int last_idx = min(max(mcount - 1, 0), SEQ - 1);
  int tag_last = tags[(size_t)last_idx * BATCH + b];
  tag_last = min(max(tag_last, 0), NTAGS - 1);
  float num = np + end_t[tag_last];

  if (lane == 0) llh[b] = num - den;
}

__global__ __launch_bounds__(64) void crf_reduce_kernel(
    const float* __restrict__ llh, float* __restrict__ out)
{
  const int lane = threadIdx.x;
  float v = 0.0f;
#pragma unroll
  for (int k = 0; k < BATCH / 64; ++k)
    v += llh[lane + 64 * k];
#pragma unroll
  for (int off = 32; off > 0; off >>= 1)
    v += __shfl_xor(v, off);
  if (lane == 0) out[0] = v * (1.0f / (float)BATCH);
}

extern "C" void kernel_launch(void* const* d_in, const int* in_sizes, int n_in,
                              void* d_out, int out_size, void* d_ws, size_t ws_size,
                              hipStream_t stream) {
  const float* em   = (const float*)d_in[0];
  const int*   tg   = (const int*)  d_in[1];
  const int*   mask = (const int*)  d_in[2];
  const float* st   = (const float*)d_in[3];
  const float* en   = (const float*)d_in[4];
  const float* tr   = (const float*)d_in[5];
  float* llh = (float*)d_ws;

  crf_chain_kernel<<<BATCH, 64, 0, stream>>>(em, tg, mask, st, en, tr, llh);
  crf_reduce_kernel<<<1, 64, 0, stream>>>(llh, (float*)d_out);
}

// Round 4
// 298.236 us; speedup vs baseline: 1.9682x; 1.3043x over previous
//
#include <hip/hip_runtime.h>

#define SEQ    1024
#define BATCH  512
#define NTAGS  48
#define CH     16             // recurrence steps per staged chunk
#define NCHUNK (SEQ / CH)     // 64

// One wave per chain. Lane j owns W[:,j]=exp(trans[:,j]) and linear score a[j].
// Emissions staged 16 steps at a time through double-buffered LDS; the 3
// float4 global loads per chunk are issued one full chunk (~5000 cy) before
// their ds_write, so HBM latency never touches the per-step critical path.
// Per step: a'[j] = (sum_i a[i]*W[i,j]) * exp(em[t,j]); renorm every 8 steps
// by the (free) max of the incoming a, absorbed into log-offset c.
__global__ __launch_bounds__(64) void crf_chain_kernel(
    const float* __restrict__ em,     // [SEQ,BATCH,NTAGS] f32
    const int*   __restrict__ tags,   // [SEQ,BATCH] int32
    const int*   __restrict__ mask,   // [SEQ,BATCH] int32
    const float* __restrict__ start_t,// [NTAGS]
    const float* __restrict__ end_t,  // [NTAGS]
    const float* __restrict__ trans,  // [NTAGS,NTAGS]
    float*       __restrict__ llh)    // [BATCH]
{
  const int b    = blockIdx.x;
  const int lane = threadIdx.x;          // single wave
  const bool act = lane < NTAGS;
  const int jj   = act ? lane : 0;

  __shared__ __align__(16) float sa[64];
  __shared__ __align__(16) float sem[2][CH * NTAGS];  // 2 x 768 floats
  __shared__ int smask[SEQ];

  // stage mask column; detect all-ones
  int myall = 1;
#pragma unroll
  for (int k = 0; k < SEQ / 64; ++k) {
    int t = lane + 64 * k;
    int v = mask[(size_t)t * BATCH + b];
    smask[t] = v;
    myall &= (v != 0) ? 1 : 0;
  }
  const bool allones = (__ballot(myall) == ~0ull);

  float wcol[NTAGS];
#pragma unroll
  for (int i = 0; i < NTAGS; ++i)
    wcol[i] = __expf(trans[i * NTAGS + jj]);

  float c = 0.0f;
  float a = act ? __expf(start_t[jj] + em[(size_t)b * NTAGS + jj]) : 0.0f;

  const size_t strideT = (size_t)BATCH * NTAGS;
  const float* embase  = em + (size_t)b * NTAGS;

  // chunk-load addressing: flat element q*256 + lane*4 -> (step, offset)
  const int idx0 = lane * 4;
  const int s0 = (idx0      ) / 48, w0 = (idx0      ) % 48;
  const int s1 = (idx0 + 256) / 48, w1 = (idx0 + 256) % 48;
  const int s2 = (idx0 + 512) / 48, w2 = (idx0 + 512) % 48;

  float4 rA0, rA1, rA2, rB0, rB1, rB2;

#define LOADCH(R0, R1, R2, ck) do {                                   \
    const float* p_ = embase + (size_t)(ck) * CH * strideT;           \
    R0 = *(const float4*)(p_ + (size_t)s0 * strideT + w0);            \
    R1 = *(const float4*)(p_ + (size_t)s1 * strideT + w1);            \
    R2 = *(const float4*)(p_ + (size_t)s2 * strideT + w2);            \
  } while (0)

#define WRITECH(buf, R0, R1, R2) do {                                 \
    *(float4*)&(buf)[idx0      ] = R0;                                \
    *(float4*)&(buf)[idx0 + 256] = R1;                                \
    *(float4*)&(buf)[idx0 + 512] = R2;                                \
  } while (0)

#define MATVEC(S_, MX_, DOMX_) do {                                   \
    float ac0 = 0.f, ac1 = 0.f, ac2 = 0.f, ac3 = 0.f;                 \
    _Pragma("unroll")                                                 \
    for (int i_ = 0; i_ < NTAGS; i_ += 4) {                           \
      float4 v_ = *(const float4*)&sa[i_];                            \
      ac0 = fmaf(v_.x, wcol[i_ + 0], ac0);                            \
      ac1 = fmaf(v_.y, wcol[i_ + 1], ac1);                            \
      ac2 = fmaf(v_.z, wcol[i_ + 2], ac2);                            \
      ac3 = fmaf(v_.w, wcol[i_ + 3], ac3);                            \
      if (DOMX_)                                                      \
        MX_ = fmaxf(MX_, fmaxf(fmaxf(v_.x, v_.y), fmaxf(v_.z, v_.w)));\
    }                                                                 \
    S_ = (ac0 + ac1) + (ac2 + ac3);                                   \
  } while (0)

  // One step at compile-time position p. SB = current chunk, SN = next chunk.
#define STEP(p, SB, SN, T0, MASKED) do {                              \
    float emn_;                                                       \
    if ((p) < CH - 1) emn_ = (SB)[((p) + 1) * NTAGS + jj];            \
    else              emn_ = (SN)[jj];                                \
    int mk_ = 1;                                                      \
    if (MASKED) mk_ = smask[(T0) + (p)];                              \
    sa[lane] = a;                                                     \
    asm volatile("s_waitcnt lgkmcnt(0)" ::: "memory");                \
    float s_, mx_ = 0.f;                                              \
    if (((p) & 7) == 1) {                                             \
      MATVEC(s_, mx_, 1);                                             \
      float rm_ = __builtin_amdgcn_rcpf(mx_);                         \
      c += __logf(mx_);                                               \
      float na_ = act ? s_ * ex : 0.0f;                               \
      a = ((MASKED) ? (mk_ ? na_ : a) : na_) * rm_;                   \
    } else {                                                          \
      MATVEC(s_, mx_, 0);                                             \
      float na_ = act ? s_ * ex : 0.0f;                               \
      a = (MASKED) ? (mk_ ? na_ : a) : na_;                           \
    }                                                                 \
    ex = __expf(emn_);                                                \
  } while (0)

#define STEPS16(SB, SN, T0, PSTART, MASKED) do {                      \
    _Pragma("unroll")                                                 \
    for (int p_ = (PSTART); p_ < CH; ++p_)                            \
      STEP(p_, SB, SN, T0, MASKED);                                   \
  } while (0)

  float ex = __expf(embase[1 * strideT + jj]);   // exp(em[t=1])

  // prologue: sem[0]=chunk0, sem[1]=chunk1, rA=chunk2 (in flight)
  LOADCH(rA0, rA1, rA2, 0);
  LOADCH(rB0, rB1, rB2, 1);
  WRITECH(sem[0], rA0, rA1, rA2);
  LOADCH(rA0, rA1, rA2, 2);
  WRITECH(sem[1], rB0, rB1, rB2);
  asm volatile("s_waitcnt lgkmcnt(0)" ::: "memory");

#define CHAIN_LOOP(MASKED) do {                                       \
    STEPS16(sem[0], sem[1], 0, 1, MASKED);  /* chunk0: t=1..15 */     \
    for (int ci = 1; ci <= NCHUNK - 3; ci += 2) {                     \
      WRITECH(sem[0], rA0, rA1, rA2);       /* chunk ci+1 */          \
      LOADCH(rB0, rB1, rB2, ci + 2);                                  \
      asm volatile("s_waitcnt lgkmcnt(0)" ::: "memory");              \
      STEPS16(sem[1], sem[0], ci * CH, 0, MASKED);                    \
      WRITECH(sem[1], rB0, rB1, rB2);       /* chunk ci+2 */          \
      {                                                               \
        int cn_ = (ci + 3 < NCHUNK) ? ci + 3 : NCHUNK - 1;            \
        LOADCH(rA0, rA1, rA2, cn_);                                   \
      }                                                               \
      asm volatile("s_waitcnt lgkmcnt(0)" ::: "memory");              \
      STEPS16(sem[0], sem[1], (ci + 1) * CH, 0, MASKED);              \
    }                                                                 \
    STEPS16(sem[1], sem[1], (NCHUNK - 1) * CH, 0, MASKED);            \
  } while (0)

  if (allones) CHAIN_LOOP(0);
  else         CHAIN_LOOP(1);

  // denominator: c + log(sum_j a[j]*exp(end[j]))
  float v = act ? a * __expf(end_t[jj]) : 0.0f;
#pragma unroll
  for (int off = 32; off > 0; off >>= 1)
    v += __shfl_xor(v, off);
  float den = c + __logf(v);

  // numerator: tag-path score; lanes parallel over t
  float np = 0.0f;
  int   mcount = 0;
  for (int t = lane; t < SEQ; t += 64) {
    int tag_t = tags[(size_t)t * BATCH + b];
    tag_t = min(max(tag_t, 0), NTAGS - 1);
    int mk = smask[t];
    float e = em[(size_t)t * strideT + (size_t)b * NTAGS + tag_t];
    if (t == 0) {
      np += start_t[tag_t] + e;
    } else {
      int tag_p = tags[(size_t)(t - 1) * BATCH + b];
      tag_p = min(max(tag_p, 0), NTAGS - 1);
      np += (trans[tag_p * NTAGS + tag_t] + e) * (float)mk;
    }
    mcount += (mk != 0) ? 1 : 0;
  }
#pragma unroll
  for (int off = 32; off > 0; off >>= 1) {
    np     += __shfl_xor(np, off);
    mcount += __shfl_xor(mcount, off);
  }
  int last_idx = min(max(mcount - 1, 0), SEQ - 1);
  int tag_last = tags[(size_t)last_idx * BATCH + b];
  tag_last = min(max(tag_last, 0), NTAGS - 1);
  float num = np + end_t[tag_last];

  if (lane == 0) llh[b] = num - den;
}

__global__ __launch_bounds__(64) void crf_reduce_kernel(
    const float* __restrict__ llh, float* __restrict__ out)
{
  const int lane = threadIdx.x;
  float v = 0.0f;
#pragma unroll
  for (int k = 0; k < BATCH / 64; ++k)
    v += llh[lane + 64 * k];
#pragma unroll
  for (int off = 32; off > 0; off >>= 1)
    v += __shfl_xor(v, off);
  if (lane == 0) out[0] = v * (1.0f / (float)BATCH);
}

extern "C" void kernel_launch(void* const* d_in, const int* in_sizes, int n_in,
                              void* d_out, int out_size, void* d_ws, size_t ws_size,
                              hipStream_t stream) {
  const float* em   = (const float*)d_in[0];
  const int*   tg   = (const int*)  d_in[1];
  const int*   mask = (const int*)  d_in[2];
  const float* st   = (const float*)d_in[3];
  const float* en   = (const float*)d_in[4];
  const float* tr   = (const float*)d_in[5];
  float* llh = (float*)d_ws;

  crf_chain_kernel<<<BATCH, 64, 0, stream>>>(em, tg, mask, st, en, tr, llh);
  crf_reduce_kernel<<<1, 64, 0, stream>>>(llh, (float*)d_out);
}

// Round 5
// 211.051 us; speedup vs baseline: 2.7813x; 1.4131x over previous
//
#include <hip/hip_runtime.h>

#define SEQ    1024
#define BATCH  512
#define NTAGS  48
#define CH     8              // recurrence steps per register-staged chunk
#define NCHUNK (SEQ / CH)     // 128

// One wave per chain. Lane j owns W[:,j]=exp(trans[:,j]) and linear score a[j].
// Broadcast of a[] done with 48 compile-time v_readlane (VGPR->SGPR, ~4cy)
// feeding v_fma with one SGPR operand -- NO LDS round trip in the recurrence.
// Emissions double-buffered in registers, chunk of 8 steps loaded ~1700cy
// ahead (fully unrolled -> static register indices). Renorm every 4 steps by
// a[0] (positive mixing keeps it > 0), absorbed into log-offset c.
__global__ __launch_bounds__(64) void crf_chain_kernel(
    const float* __restrict__ em,     // [SEQ,BATCH,NTAGS] f32
    const int*   __restrict__ tags,   // [SEQ,BATCH] int32
    const int*   __restrict__ mask,   // [SEQ,BATCH] int32
    const float* __restrict__ start_t,// [NTAGS]
    const float* __restrict__ end_t,  // [NTAGS]
    const float* __restrict__ trans,  // [NTAGS,NTAGS]
    float*       __restrict__ llh)    // [BATCH]
{
  const int b    = blockIdx.x;
  const int lane = threadIdx.x;          // single wave
  const bool act = lane < NTAGS;
  const int jj   = act ? lane : 0;

  __shared__ int smask[SEQ];

  // stage mask column; detect all-ones
  int myall = 1;
#pragma unroll
  for (int k = 0; k < SEQ / 64; ++k) {
    int t = lane + 64 * k;
    int v = mask[(size_t)t * BATCH + b];
    smask[t] = v;
    myall &= (v != 0) ? 1 : 0;
  }
  const bool allones = (__ballot(myall) == ~0ull);

  float wcol[NTAGS];
#pragma unroll
  for (int i = 0; i < NTAGS; ++i)
    wcol[i] = __expf(trans[i * NTAGS + jj]);

  const size_t strideT = (size_t)BATCH * NTAGS;
  const float* emcol   = em + (size_t)b * NTAGS + jj;   // per-lane column

  float c = 0.0f;
  float a = act ? __expf(start_t[jj] + emcol[0]) : 0.0f;

  float emA[CH], emB[CH];

#define RL(k) __int_as_float(__builtin_amdgcn_readlane(__float_as_int(a), (k)))

#define LOADCH(R, ci) do {                                            \
    const float* pp_ = emcol + (size_t)(ci) * CH * strideT;           \
    _Pragma("unroll")                                                 \
    for (int p_ = 0; p_ < CH; ++p_)                                   \
      (R)[p_] = pp_[(size_t)p_ * strideT];                            \
  } while (0)

  // One recurrence step at compile-time position p (t = ci*CH + p).
#define STEP(p, CUR, NXT, T0, MASKED) do {                            \
    float ac0 = 0.f, ac1 = 0.f, ac2 = 0.f, ac3 = 0.f;                 \
    _Pragma("unroll")                                                 \
    for (int k_ = 0; k_ < NTAGS; k_ += 4) {                           \
      ac0 = fmaf(RL(k_ + 0), wcol[k_ + 0], ac0);                      \
      ac1 = fmaf(RL(k_ + 1), wcol[k_ + 1], ac1);                      \
      ac2 = fmaf(RL(k_ + 2), wcol[k_ + 2], ac2);                      \
      ac3 = fmaf(RL(k_ + 3), wcol[k_ + 3], ac3);                      \
    }                                                                 \
    float s_  = (ac0 + ac1) + (ac2 + ac3);                            \
    float na_ = act ? s_ * ex : 0.0f;                                 \
    if (MASKED) { int mk_ = smask[(T0) + (p)]; na_ = mk_ ? na_ : a; } \
    a = na_;                                                          \
    if (((p) & 3) == 3) {                                             \
      float m0_ = RL(0);              /* >0: positive mixing */       \
      c += __logf(m0_);                                               \
      a *= __builtin_amdgcn_rcpf(m0_);                                \
    }                                                                 \
    float emn_ = ((p) < CH - 1) ? (CUR)[(p) + 1] : (NXT)[0];          \
    ex = __expf(emn_);                                                \
  } while (0)

  // Chunk ci: prefetch chunk ci+1 into NXT, then run steps PSTART..CH-1.
#define CHUNK(CUR, NXT, ci, PSTART, MASKED) do {                      \
    int cin_ = ((ci) + 1 < NCHUNK) ? (ci) + 1 : NCHUNK - 1;           \
    LOADCH(NXT, cin_);                                                \
    _Pragma("unroll")                                                 \
    for (int p_ = (PSTART); p_ < CH; ++p_)                            \
      STEP(p_, CUR, NXT, (ci) * CH, MASKED);                          \
  } while (0)

  LOADCH(emA, 0);
  float ex = __expf(emA[1]);           // for t=1 (one vmcnt wait, prologue)

#define CHAIN_LOOP(MASKED) do {                                       \
    CHUNK(emA, emB, 0, 1, MASKED);            /* t = 1..7   */        \
    for (int ci = 1; ci <= NCHUNK - 3; ci += 2) {                     \
      CHUNK(emB, emA, ci,     0, MASKED);                             \
      CHUNK(emA, emB, ci + 1, 0, MASKED);                             \
    }                                                                 \
    CHUNK(emB, emA, NCHUNK - 1, 0, MASKED);   /* t = 1016..1023 */    \
  } while (0)

  if (allones) CHAIN_LOOP(0);
  else         CHAIN_LOOP(1);

  // denominator: c + log(sum_j a[j]*exp(end[j]))
  float v = act ? a * __expf(end_t[jj]) : 0.0f;
#pragma unroll
  for (int off = 32; off > 0; off >>= 1)
    v += __shfl_xor(v, off);
  float den = c + __logf(v);

  // numerator: tag-path score; lanes parallel over t
  float np = 0.0f;
  int   mcount = 0;
  for (int t = lane; t < SEQ; t += 64) {
    int tag_t = tags[(size_t)t * BATCH + b];
    tag_t = min(max(tag_t, 0), NTAGS - 1);
    int mk = smask[t];
    float e = em[(size_t)t * strideT + (size_t)b * NTAGS + tag_t];
    if (t == 0) {
      np += start_t[tag_t] + e;
    } else {
      int tag_p = tags[(size_t)(t - 1) * BATCH + b];
      tag_p = min(max(tag_p, 0), NTAGS - 1);
      np += (trans[tag_p * NTAGS + tag_t] + e) * (float)mk;
    }
    mcount += (mk != 0) ? 1 : 0;
  }
#pragma unroll
  for (int off = 32; off > 0; off >>= 1) {
    np     += __shfl_xor(np, off);
    mcount += __shfl_xor(mcount, off);
  }
  int last_idx = min(max(mcount - 1, 0), SEQ - 1);
  int tag_last = tags[(size_t)last_idx * BATCH + b];
  tag_last = min(max(tag_last, 0), NTAGS - 1);
  float num = np + end_t[tag_last];

  if (lane == 0) llh[b] = num - den;
}

__global__ __launch_bounds__(64) void crf_reduce_kernel(
    const float* __restrict__ llh, float* __restrict__ out)
{
  const int lane = threadIdx.x;
  float v = 0.0f;
#pragma unroll
  for (int k = 0; k < BATCH / 64; ++k)
    v += llh[lane + 64 * k];
#pragma unroll
  for (int off = 32; off > 0; off >>= 1)
    v += __shfl_xor(v, off);
  if (lane == 0) out[0] = v * (1.0f / (float)BATCH);
}

extern "C" void kernel_launch(void* const* d_in, const int* in_sizes, int n_in,
                              void* d_out, int out_size, void* d_ws, size_t ws_size,
                              hipStream_t stream) {
  const float* em   = (const float*)d_in[0];
  const int*   tg   = (const int*)  d_in[1];
  const int*   mask = (const int*)  d_in[2];
  const float* st   = (const float*)d_in[3];
  const float* en   = (const float*)d_in[4];
  const float* tr   = (const float*)d_in[5];
  float* llh = (float*)d_ws;

  crf_chain_kernel<<<BATCH, 64, 0, stream>>>(em, tg, mask, st, en, tr, llh);
  crf_reduce_kernel<<<1, 64, 0, stream>>>(llh, (float*)d_out);
}

// Round 6
// 203.242 us; speedup vs baseline: 2.8882x; 1.0384x over previous
//
#include <hip/hip_runtime.h>

#define SEQ    1024
#define BATCH  512
#define NTAGS  48
#define CH     8              // recurrence steps per register-staged chunk
#define NCHUNK (SEQ / CH)     // 128

// One wave per chain. Lane j owns W[:,j]=exp(trans[:,j]) and linear score a[j].
// Broadcast of a[] via 48 compile-time v_readlane, but scheduled in 3 groups
// of 16 with sched_barrier(0) fences so group g's readlanes interleave with
// group g-1's FMAs -- the VALU-write-SGPR -> VALU-read-SGPR wait-state hazard
// is paid ~3x/step instead of 48x/step. 8 accumulators halve FMA chain depth.
// Renorm every 4 steps pivots on the PRE-update a[0] (g0[0], already
// broadcast) so rcp/log are off the serial critical path.
__global__ __launch_bounds__(64) void crf_chain_kernel(
    const float* __restrict__ em,     // [SEQ,BATCH,NTAGS] f32
    const int*   __restrict__ tags,   // [SEQ,BATCH] int32
    const int*   __restrict__ mask,   // [SEQ,BATCH] int32
    const float* __restrict__ start_t,// [NTAGS]
    const float* __restrict__ end_t,  // [NTAGS]
    const float* __restrict__ trans,  // [NTAGS,NTAGS]
    float*       __restrict__ llh)    // [BATCH]
{
  const int b    = blockIdx.x;
  const int lane = threadIdx.x;          // single wave
  const bool act = lane < NTAGS;
  const int jj   = act ? lane : 0;

  __shared__ int smask[SEQ];

  // stage mask column; detect all-ones
  int myall = 1;
#pragma unroll
  for (int k = 0; k < SEQ / 64; ++k) {
    int t = lane + 64 * k;
    int v = mask[(size_t)t * BATCH + b];
    smask[t] = v;
    myall &= (v != 0) ? 1 : 0;
  }
  const bool allones = (__ballot(myall) == ~0ull);

  float wcol[NTAGS];
#pragma unroll
  for (int i = 0; i < NTAGS; ++i)
    wcol[i] = __expf(trans[i * NTAGS + jj]);

  const size_t strideT = (size_t)BATCH * NTAGS;
  const float* emcol   = em + (size_t)b * NTAGS + jj;   // per-lane column

  float c = 0.0f;
  // lanes >=48 mirror lane 0 (jj clamped): harmless, never read by readlane
  float a = __expf(start_t[jj] + emcol[0]);

  float emA[CH], emB[CH];

#define RL(k) __int_as_float(__builtin_amdgcn_readlane(__float_as_int(a), (k)))

#define LOADCH(R, ci) do {                                            \
    const float* pp_ = emcol + (size_t)(ci) * CH * strideT;           \
    _Pragma("unroll")                                                 \
    for (int p_ = 0; p_ < CH; ++p_)                                   \
      (R)[p_] = pp_[(size_t)p_ * strideT];                            \
  } while (0)

#define FMAG(G, base)                                                 \
    _Pragma("unroll")                                                 \
    for (int q_ = 0; q_ < 16; ++q_)                                   \
      acc_[q_ & 7] = fmaf((G)[q_], wcol[(base) + q_], acc_[q_ & 7]);

  // One recurrence step at compile-time position p (t = T0 + p).
#define STEP(p, CUR, NXT, T0, MASKED) do {                            \
    float g0_[16], g1_[16], g2_[16];                                  \
    float acc_[8];                                                    \
    _Pragma("unroll") for (int q_ = 0; q_ < 8;  ++q_) acc_[q_] = 0.f; \
    _Pragma("unroll") for (int q_ = 0; q_ < 16; ++q_) g0_[q_] = RL(q_);\
    __builtin_amdgcn_sched_barrier(0);                                \
    float rm_ = 0.f;                                                  \
    if (((p) & 3) == 3) rm_ = __builtin_amdgcn_rcpf(g0_[0]);          \
    _Pragma("unroll") for (int q_ = 0; q_ < 16; ++q_) g1_[q_] = RL(16 + q_);\
    FMAG(g0_, 0);                                                     \
    __builtin_amdgcn_sched_barrier(0);                                \
    _Pragma("unroll") for (int q_ = 0; q_ < 16; ++q_) g2_[q_] = RL(32 + q_);\
    FMAG(g1_, 16);                                                    \
    __builtin_amdgcn_sched_barrier(0);                                \
    FMAG(g2_, 32);                                                    \
    float s_ = ((acc_[0] + acc_[1]) + (acc_[2] + acc_[3]))            \
             + ((acc_[4] + acc_[5]) + (acc_[6] + acc_[7]));           \
    float na_ = s_ * ex;                                              \
    if (((p) & 3) == 3) {                                             \
      c += __logf(g0_[0]);                                            \
      na_ *= rm_;                                                     \
      if (MASKED) { int mk_ = smask[(T0) + (p)];                      \
                    a = mk_ ? na_ : a * rm_; }                        \
      else a = na_;                                                   \
    } else {                                                          \
      if (MASKED) { int mk_ = smask[(T0) + (p)]; a = mk_ ? na_ : a; } \
      else a = na_;                                                   \
    }                                                                 \
    float emn_ = ((p) < CH - 1) ? (CUR)[(p) + 1] : (NXT)[0];          \
    ex = __expf(emn_);                                                \
  } while (0)

  // Chunk ci: prefetch chunk ci+1 into NXT, then run steps PSTART..CH-1.
#define CHUNK(CUR, NXT, ci, PSTART, MASKED) do {                      \
    int cin_ = ((ci) + 1 < NCHUNK) ? (ci) + 1 : NCHUNK - 1;           \
    LOADCH(NXT, cin_);                                                \
    _Pragma("unroll")                                                 \
    for (int p_ = (PSTART); p_ < CH; ++p_)                            \
      STEP(p_, CUR, NXT, (ci) * CH, MASKED);                          \
  } while (0)

  LOADCH(emA, 0);
  float ex = __expf(emA[1]);           // for t=1 (one vmcnt wait, prologue)

#define CHAIN_LOOP(MASKED) do {                                       \
    CHUNK(emA, emB, 0, 1, MASKED);            /* t = 1..7   */        \
    for (int ci = 1; ci <= NCHUNK - 3; ci += 2) {                     \
      CHUNK(emB, emA, ci,     0, MASKED);                             \
      CHUNK(emA, emB, ci + 1, 0, MASKED);                             \
    }                                                                 \
    CHUNK(emB, emA, NCHUNK - 1, 0, MASKED);   /* t = 1016..1023 */    \
  } while (0)

  if (allones) CHAIN_LOOP(0);
  else         CHAIN_LOOP(1);

  // denominator: c + log(sum_j a[j]*exp(end[j]))
  float v = act ? a * __expf(end_t[jj]) : 0.0f;
#pragma unroll
  for (int off = 32; off > 0; off >>= 1)
    v += __shfl_xor(v, off);
  float den = c + __logf(v);

  // numerator: tag-path score; lanes parallel over t
  float np = 0.0f;
  int   mcount = 0;
  for (int t = lane; t < SEQ; t += 64) {
    int tag_t = tags[(size_t)t * BATCH + b];
    tag_t = min(max(tag_t, 0), NTAGS - 1);
    int mk = smask[t];
    float e = em[(size_t)t * strideT + (size_t)b * NTAGS + tag_t];
    if (t == 0) {
      np += start_t[tag_t] + e;
    } else {
      int tag_p = tags[(size_t)(t - 1) * BATCH + b];
      tag_p = min(max(tag_p, 0), NTAGS - 1);
      np += (trans[tag_p * NTAGS + tag_t] + e) * (float)mk;
    }
    mcount += (mk != 0) ? 1 : 0;
  }
#pragma unroll
  for (int off = 32; off > 0; off >>= 1) {
    np     += __shfl_xor(np, off);
    mcount += __shfl_xor(mcount, off);
  }
  int last_idx = min(max(mcount - 1, 0), SEQ - 1);
  int tag_last = tags[(size_t)last_idx * BATCH + b];
  tag_last = min(max(tag_last, 0), NTAGS - 1);
  float num = np + end_t[tag_last];

  if (lane == 0) llh[b] = num - den;
}

__global__ __launch_bounds__(64) void crf_reduce_kernel(
    const float* __restrict__ llh, float* __restrict__ out)
{
  const int lane = threadIdx.x;
  float v = 0.0f;
#pragma unroll
  for (int k = 0; k < BATCH / 64; ++k)
    v += llh[lane + 64 * k];
#pragma unroll
  for (int off = 32; off > 0; off >>= 1)
    v += __shfl_xor(v, off);
  if (lane == 0) out[0] = v * (1.0f / (float)BATCH);
}

extern "C" void kernel_launch(void* const* d_in, const int* in_sizes, int n_in,
                              void* d_out, int out_size, void* d_ws, size_t ws_size,
                              hipStream_t stream) {
  const float* em   = (const float*)d_in[0];
  const int*   tg   = (const int*)  d_in[1];
  const int*   mask = (const int*)  d_in[2];
  const float* st   = (const float*)d_in[3];
  const float* en   = (const float*)d_in[4];
  const float* tr   = (const float*)d_in[5];
  float* llh = (float*)d_ws;

  crf_chain_kernel<<<BATCH, 64, 0, stream>>>(em, tg, mask, st, en, tr, llh);
  crf_reduce_kernel<<<1, 64, 0, stream>>>(llh, (float*)d_out);
}